// Round 1
// baseline (12.071 us; speedup 1.0000x reference)
//
#include <hip/hip_runtime.h>

// GCN on a fully-connected graph collapses:
//   deg[i] = N for all i  ->  norm = 1/N on every edge (incl. self-loop)
//   gcn_conv(x) row d = (1/N) * sum_j (x_j @ W) + b   (same for every d)
// => layer1: h1 = relu(colmean(x) @ W1 + b1)          [128]
//    layer2: h2 = relu(h1 @ W2 + b2)                  [64]   (all rows of h equal)
//    output: mean(h2) broadcast to all N nodes        [1024]
// Single block, single kernel, fully deterministic fp32.

#define N_NODES 1024
#define IN_DIM  64
#define HID_DIM 128
#define OUT_DIM 64

__global__ __launch_bounds__(1024) void gcn_collapsed_kernel(
    const float* __restrict__ x,    // [1024][64]
    const float* __restrict__ W1,   // [64][128]
    const float* __restrict__ b1,   // [128]
    const float* __restrict__ W2,   // [128][64]
    const float* __restrict__ b2,   // [64]
    float* __restrict__ out)        // [1024]
{
    __shared__ float s_part[64][64];   // [rowgroup][col] partial column sums (16 KB)
    __shared__ float s_mean[IN_DIM];   // colmean(x)
    __shared__ float s_t[HID_DIM];     // relu(mean @ W1 + b1)
    __shared__ float s_u[OUT_DIM];     // relu(t @ W2 + b2)

    const int tid = threadIdx.x;

    // ---- Stage A: column sums of x (1024 x 64), float4 loads, coalesced ----
    // thread -> rowgroup rg = tid/16 (64 groups), col-quad cq = tid%16
    const int rg = tid >> 4;
    const int cq = tid & 15;
    const float4* x4 = reinterpret_cast<const float4*>(x);
    float4 acc = make_float4(0.f, 0.f, 0.f, 0.f);
    #pragma unroll
    for (int it = 0; it < 16; ++it) {
        float4 v = x4[(rg + (it << 6)) * (IN_DIM / 4) + cq];
        acc.x += v.x; acc.y += v.y; acc.z += v.z; acc.w += v.w;
    }
    const int c0 = cq << 2;
    s_part[rg][c0 + 0] = acc.x;
    s_part[rg][c0 + 1] = acc.y;
    s_part[rg][c0 + 2] = acc.z;
    s_part[rg][c0 + 3] = acc.w;
    __syncthreads();

    if (tid < IN_DIM) {
        float s = 0.f;
        #pragma unroll 8
        for (int g = 0; g < 64; ++g) s += s_part[g][tid];
        s_mean[tid] = s * (1.0f / (float)N_NODES);
    }
    __syncthreads();

    // ---- Stage B: t = relu(colmean(x) @ W1 + b1), 128 outputs ----
    if (tid < HID_DIM) {
        float a = b1[tid];
        #pragma unroll 8
        for (int c = 0; c < IN_DIM; ++c) a += s_mean[c] * W1[c * HID_DIM + tid];
        s_t[tid] = fmaxf(a, 0.0f);
    }
    __syncthreads();

    // ---- Stage C: u = relu(t @ W2 + b2), 64 outputs ----
    if (tid < OUT_DIM) {
        float a = b2[tid];
        #pragma unroll 8
        for (int k = 0; k < HID_DIM; ++k) a += s_t[k] * W2[k * OUT_DIM + tid];
        s_u[tid] = fmaxf(a, 0.0f);
    }
    __syncthreads();

    // ---- Stage D: scalar = mean(u); broadcast to all 1024 outputs ----
    // Every thread redundantly computes the same sum (LDS broadcast reads are free),
    // guaranteeing bit-identical values across the output.
    float m = 0.f;
    #pragma unroll 8
    for (int k = 0; k < OUT_DIM; ++k) m += s_u[k];
    m *= (1.0f / (float)OUT_DIM);
    out[tid] = m;
}

extern "C" void kernel_launch(void* const* d_in, const int* in_sizes, int n_in,
                              void* d_out, int out_size, void* d_ws, size_t ws_size,
                              hipStream_t stream) {
    const float* x  = (const float*)d_in[0];
    const float* W1 = (const float*)d_in[1];
    const float* b1 = (const float*)d_in[2];
    const float* W2 = (const float*)d_in[3];
    const float* b2 = (const float*)d_in[4];
    // d_in[5] = src, d_in[6] = dst: fully-connected graph -> deg == N, norm == 1/N,
    // already folded into the collapsed math above.
    float* out = (float*)d_out;

    gcn_collapsed_kernel<<<1, 1024, 0, stream>>>(x, W1, b1, W2, b2, out);
}

// Round 2
// 11.535 us; speedup vs baseline: 1.0465x; 1.0465x over previous
//
#include <hip/hip_runtime.h>

// GCN on a fully-connected graph (reference builds ALL i!=j edges, GCNConv
// re-adds self-loops) collapses:
//   deg[i] = N for all i  ->  norm = 1/N on every edge
//   gcn_conv(x) row d = (1/N) * sum_j (x_j @ W) + b   (identical for every d)
// => h1 = relu(colmean(x) @ W1 + b1)  [128]
//    h2 = relu(h1 @ W2 + b2)          [64]
//    out = mean(h2) broadcast to all N nodes.
// Single block, single kernel, deterministic fp32.
//
// R1 change: W1/W2 (64 KB) are prefetched into LDS with loads issued BEFORE
// the 256 KB x-read, so their latency hides under the BW-bound x phase.
// Stages B/C then run out of LDS (were latency-bound global loads with only
// 1-2 active waves). Accumulator chains split 4-way.

#define N_NODES 1024
#define IN_DIM  64
#define HID_DIM 128
#define OUT_DIM 64

__global__ __launch_bounds__(1024) void gcn_collapsed_kernel(
    const float* __restrict__ x,    // [1024][64]
    const float* __restrict__ W1,   // [64][128]
    const float* __restrict__ b1,   // [128]
    const float* __restrict__ W2,   // [128][64]
    const float* __restrict__ b2,   // [64]
    float* __restrict__ out)        // [1024]
{
    __shared__ float s_w1[IN_DIM * HID_DIM];    // 32 KB
    __shared__ float s_w2[HID_DIM * OUT_DIM];   // 32 KB
    __shared__ float s_part[64][64];            // 16 KB partial column sums
    __shared__ float s_mean[IN_DIM];
    __shared__ float s_t[HID_DIM];
    __shared__ float s_u[OUT_DIM];

    const int tid = threadIdx.x;

    // ---- Issue weight loads FIRST (oldest in the VMEM queue) ----
    const float4* w1_4 = reinterpret_cast<const float4*>(W1);  // 2048 x float4
    const float4* w2_4 = reinterpret_cast<const float4*>(W2);  // 2048 x float4
    float4 wa = w1_4[tid];
    float4 wb = w1_4[tid + 1024];
    float4 wc = w2_4[tid];
    float4 wd = w2_4[tid + 1024];

    // ---- Stage A: column sums of x (1024 x 64), float4 loads, coalesced ----
    const int rg = tid >> 4;      // rowgroup 0..63
    const int cq = tid & 15;      // col-quad 0..15
    const float4* x4 = reinterpret_cast<const float4*>(x);
    float4 acc = make_float4(0.f, 0.f, 0.f, 0.f);
    #pragma unroll
    for (int it = 0; it < 16; ++it) {
        float4 v = x4[(rg + (it << 6)) * (IN_DIM / 4) + cq];
        acc.x += v.x; acc.y += v.y; acc.z += v.z; acc.w += v.w;
    }

    // Park weights in LDS (loads already long complete by now).
    reinterpret_cast<float4*>(s_w1)[tid]        = wa;
    reinterpret_cast<float4*>(s_w1)[tid + 1024] = wb;
    reinterpret_cast<float4*>(s_w2)[tid]        = wc;
    reinterpret_cast<float4*>(s_w2)[tid + 1024] = wd;

    const int c0 = cq << 2;
    s_part[rg][c0 + 0] = acc.x;
    s_part[rg][c0 + 1] = acc.y;
    s_part[rg][c0 + 2] = acc.z;
    s_part[rg][c0 + 3] = acc.w;
    __syncthreads();

    // ---- Stage A-reduce: colmean over the 64 rowgroups (1 wave) ----
    if (tid < IN_DIM) {
        float p0 = 0.f, p1 = 0.f, p2 = 0.f, p3 = 0.f;
        #pragma unroll
        for (int g = 0; g < 64; g += 4) {
            p0 += s_part[g + 0][tid];
            p1 += s_part[g + 1][tid];
            p2 += s_part[g + 2][tid];
            p3 += s_part[g + 3][tid];
        }
        s_mean[tid] = ((p0 + p1) + (p2 + p3)) * (1.0f / (float)N_NODES);
    }
    __syncthreads();

    // ---- Stage B: t = relu(colmean @ W1 + b1), 128 outputs, LDS reads ----
    if (tid < HID_DIM) {
        float p0 = 0.f, p1 = 0.f, p2 = 0.f, p3 = 0.f;
        #pragma unroll
        for (int c = 0; c < IN_DIM; c += 4) {
            p0 += s_mean[c + 0] * s_w1[(c + 0) * HID_DIM + tid];
            p1 += s_mean[c + 1] * s_w1[(c + 1) * HID_DIM + tid];
            p2 += s_mean[c + 2] * s_w1[(c + 2) * HID_DIM + tid];
            p3 += s_mean[c + 3] * s_w1[(c + 3) * HID_DIM + tid];
        }
        s_t[tid] = fmaxf(((p0 + p1) + (p2 + p3)) + b1[tid], 0.0f);
    }
    __syncthreads();

    // ---- Stage C: u = relu(t @ W2 + b2), 64 outputs, LDS reads ----
    if (tid < OUT_DIM) {
        float p0 = 0.f, p1 = 0.f, p2 = 0.f, p3 = 0.f;
        #pragma unroll
        for (int k = 0; k < HID_DIM; k += 4) {
            p0 += s_t[k + 0] * s_w2[(k + 0) * OUT_DIM + tid];
            p1 += s_t[k + 1] * s_w2[(k + 1) * OUT_DIM + tid];
            p2 += s_t[k + 2] * s_w2[(k + 2) * OUT_DIM + tid];
            p3 += s_t[k + 3] * s_w2[(k + 3) * OUT_DIM + tid];
        }
        s_u[tid] = fmaxf(((p0 + p1) + (p2 + p3)) + b2[tid], 0.0f);
    }
    __syncthreads();

    // ---- Stage D: scalar = mean(u); broadcast (LDS broadcast reads) ----
    float m0 = 0.f, m1 = 0.f, m2 = 0.f, m3 = 0.f;
    #pragma unroll
    for (int k = 0; k < OUT_DIM; k += 4) {
        m0 += s_u[k + 0];
        m1 += s_u[k + 1];
        m2 += s_u[k + 2];
        m3 += s_u[k + 3];
    }
    out[tid] = ((m0 + m1) + (m2 + m3)) * (1.0f / (float)OUT_DIM);
}

extern "C" void kernel_launch(void* const* d_in, const int* in_sizes, int n_in,
                              void* d_out, int out_size, void* d_ws, size_t ws_size,
                              hipStream_t stream) {
    const float* x  = (const float*)d_in[0];
    const float* W1 = (const float*)d_in[1];
    const float* b1 = (const float*)d_in[2];
    const float* W2 = (const float*)d_in[3];
    const float* b2 = (const float*)d_in[4];
    // d_in[5] = src, d_in[6] = dst: fully-connected graph -> deg == N,
    // norm == 1/N, folded into the collapsed math above.
    float* out = (float*)d_out;

    gcn_collapsed_kernel<<<1, 1024, 0, stream>>>(x, W1, b1, W2, b2, out);
}